// Round 12
// baseline (159.463 us; speedup 1.0000x reference)
//
#include <hip/hip_runtime.h>

#pragma clang fp contract(off)

typedef unsigned int u32;
typedef unsigned long long u64;
typedef long long i64;

#define N_ROWS 32768
#define NCLS 81
#define TOPK 4096
#define IMGW_M1 1332.0f
#define IMGH_M1 799.0f

// k_cand geometry: 8 threads/row, 32 rows/block, 1024 blocks (R3-verified)
#define CAND_THREADS 256
#define RPB 32
#define CAND_GRID (N_ROWS / RPB)          // 1024
#define CPT 11
#define BLK_CAND_CAP 640                  // 32 rows * <=19 cand/row = 608 max
#define ROW_F4 ((RPB * NCLS) / 4)         // 648 float4 per block slice (exactly)

// level-1 bins: f32 bits of p in (0.05, 1.0] -> hi16 in [0x3D4C, 0x3F80]
#define H1_BASE 0x3D4Cu
#define H1_BINS 576

// sliced per-bin segments (R3-verified best: 32)
#define NSLICE 32
#define SUBCAP 384                        // per-slice-per-bin capacity (u64)
#define SEG_LDS 4096                      // binrank LDS segment cap (u64)

// two-level completion ticket: 32 groups of 32 blocks each.
// Max same-address atomic chain = 32 (~2-3us) vs R11's 1024 (~70us measured).
#define TICK_GROUPS 32
#define TICK_GSIZE (CAND_GRID / TICK_GROUPS)   // 32

// k_nms: LDS box stage cap / matrix-path cap
#define MCAP 1024
#define MMAX 512
#define NW32 16                           // MMAX/32 words per column

// fast f64 exp for d <= 0 (clamped at -45). Cody-Waite + Taylor-13.
// Relative error ~3e-16 — decisions have >= f32-ulp (6e-8) margins.
__device__ inline double fast_exp_neg(double d) {
    if (d < -45.0) return 0.0;
    const double L2E    = 1.4426950408889634074;
    const double LN2_HI = 6.93147180369123816490e-01;
    const double LN2_LO = 1.90821492927058770002e-10;
    double n = __builtin_rint(d * L2E);
    double r = __builtin_fma(-n, LN2_HI, d);
    r = __builtin_fma(-n, LN2_LO, r);
    double p = 1.0 / 6227020800.0;
    p = __builtin_fma(p, r, 1.0 / 479001600.0);
    p = __builtin_fma(p, r, 1.0 / 39916800.0);
    p = __builtin_fma(p, r, 1.0 / 3628800.0);
    p = __builtin_fma(p, r, 1.0 / 362880.0);
    p = __builtin_fma(p, r, 1.0 / 40320.0);
    p = __builtin_fma(p, r, 1.0 / 5040.0);
    p = __builtin_fma(p, r, 1.0 / 720.0);
    p = __builtin_fma(p, r, 1.0 / 120.0);
    p = __builtin_fma(p, r, 1.0 / 24.0);
    p = __builtin_fma(p, r, 1.0 / 6.0);
    p = __builtin_fma(p, r, 0.5);
    p = __builtin_fma(p, r, 1.0);
    p = __builtin_fma(p, r, 1.0);
    i64 ni = (i64)n;
    double sc = __longlong_as_double((i64)(1023 + ni) << 52);
    return p * sc;
}

// ============ k_cand: R3-verified body + HIERARCHICAL ticket tail ==========
// R11 lesson (measured): same-address device atomics serialize ~70-100ns/op;
// a flat 1024-deep ticket chain cost ~70us. Two levels (32x32) cap chains at
// 32. Correctness of the ticket+fence pattern is HW-validated (R5/R11 passed).
__global__ void __launch_bounds__(256) k_cand(const float* __restrict__ x,
                                              u32* __restrict__ binCur,
                                              u64* __restrict__ selBins,
                                              u32* __restrict__ tick1,
                                              u32* __restrict__ tick2,
                                              u32* __restrict__ sufG) {
    __shared__ float4 lx4[ROW_F4];
    __shared__ u32 lK[BLK_CAND_CAP];
    __shared__ u32 lI[BLK_CAND_CAP];
    __shared__ u32 cs[1040];
    __shared__ u32 lcnt;
    __shared__ u32 lastSh;
    __shared__ u32 Bsh;
    float* lx = (float*)lx4;
    const int t = threadIdx.x;
    if (t == 0) { lcnt = 0; Bsh = 0; }

    const float4* xv = (const float4*)x + (size_t)blockIdx.x * ROW_F4;
    for (int i = t; i < ROW_F4; i += CAND_THREADS) lx4[i] = xv[i];
    __syncthreads();

    const int rl = t >> 3;
    const int q = t & 7;
    const int c0 = q * 10;
    const int cEff = (q == 7) ? 11 : 10;
    const int row = blockIdx.x * RPB + rl;
    const float* xr = lx + rl * NCLS;

    float v[CPT];
    #pragma unroll
    for (int i = 0; i < CPT; i++) v[i] = (i < cEff) ? xr[c0 + i] : -1.0e30f;

    float m = v[0];
    #pragma unroll
    for (int i = 1; i < CPT; i++) m = fmaxf(m, v[i]);
    m = fmaxf(m, __shfl_xor(m, 1));
    m = fmaxf(m, __shfl_xor(m, 2));
    m = fmaxf(m, __shfl_xor(m, 4));

    double e[CPT];
    #pragma unroll
    for (int i = 0; i < CPT; i++) {
        if (i < cEff) {
            float d = v[i] - m;                   // f32 subtract, as reference
            e[i] = fast_exp_neg((double)d);
        } else e[i] = 0.0;
    }
    double s = 0.0;
    #pragma unroll
    for (int i = 0; i < CPT; i++) if (i < cEff) s += e[i];
    s += __shfl_xor(s, 1);
    s += __shfl_xor(s, 2);
    s += __shfl_xor(s, 4);

    const double THRMID = (double)0.05f + 0x1.0p-29;
    double ethr = THRMID * s;
    #pragma unroll
    for (int i = 0; i < CPT; i++) {
        int c = c0 + i;
        if (i < cEff && c != 0 && e[i] > ethr) {
            float pf = (float)(e[i] / s);         // exact f64 division, rare
            u32 slot = atomicAdd(&lcnt, 1u);
            lK[slot] = __float_as_uint(pf);
            lI[slot] = (u32)(row * NCLS + c);
        }
    }
    __syncthreads();

    // sliced scatter: wave lanes hit DISTINCT staged cands;
    // per-address chains <= ~44 (hot bin / 32 slices)
    const u32 tot = lcnt;
    const u32 sbase = (blockIdx.x & (NSLICE - 1)) * H1_BINS;
    for (u32 i = t; i < tot; i += CAND_THREADS) {
        u32 key = lK[i];
        u32 b = (key >> 16) - H1_BASE;            // always in [0, 576)
        u32 pos = atomicAdd(&binCur[sbase + b], 1u);
        if (pos < (u32)SUBCAP)
            selBins[(size_t)(sbase + b) * SUBCAP + pos] =
                ((u64)key << 32) | (u64)(0xFFFFFFFFu - lI[i]);
    }
    __syncthreads();                              // drains this block's atomics

    // ---- two-level ticket: group-last -> global-last publishes ----
    if (t == 0) {
        __threadfence();                          // release this block's work
        u32 g = blockIdx.x & (TICK_GROUPS - 1);   // group-mates spread in launch
        u32 tk1 = __hip_atomic_fetch_add(&tick1[g], 1u, __ATOMIC_ACQ_REL,
                                         __HIP_MEMORY_SCOPE_AGENT);
        u32 last = 0;
        if (tk1 == (u32)(TICK_GSIZE - 1)) {       // last in group (32 such blocks)
            u32 tk2 = __hip_atomic_fetch_add(tick2, 1u, __ATOMIC_ACQ_REL,
                                             __HIP_MEMORY_SCOPE_AGENT);
            last = (tk2 == (u32)(TICK_GROUPS - 1)) ? 1u : 0u;
        }
        lastSh = last;
        if (last) __threadfence();                // acquire all blocks' atomics
    }
    __syncthreads();
    if (!lastSh) return;

    // reduce 32x576 -> cs, inclusive suffix scan over 1024 (k_midlite values)
    {
        u32 s0 = 0, s1 = 0, s2 = 0;
        const bool g1 = (t + 256) < H1_BINS;
        const bool g2 = (t + 512) < H1_BINS;
        #pragma unroll 4
        for (int j = 0; j < NSLICE; j++) {
            const u32* hp = binCur + j * H1_BINS;
            s0 += hp[t];
            if (g1) s1 += hp[t + 256];
            if (g2) s2 += hp[t + 512];
        }
        cs[t] = s0;
        cs[t + 256] = g1 ? s1 : 0u;
        cs[t + 512] = g2 ? s2 : 0u;
        cs[t + 768] = 0u;
    }
    __syncthreads();
    for (int d = 1; d < 1024; d <<= 1) {
        u32 a0 = (t + d < 1024) ? cs[t + d] : 0u;
        u32 a1 = (t + 256 + d < 1024) ? cs[t + 256 + d] : 0u;
        u32 a2 = (t + 512 + d < 1024) ? cs[t + 512 + d] : 0u;
        u32 a3 = (t + 768 + d < 1024) ? cs[t + 768 + d] : 0u;
        __syncthreads();
        cs[t] += a0; cs[t + 256] += a1; cs[t + 512] += a2; cs[t + 768] += a3;
        __syncthreads();
    }
    #pragma unroll
    for (int qq = 0; qq < 3; qq++) {
        int i = t + qq * 256;
        if (i < H1_BINS) {
            if (cs[i] >= (u32)TOPK && cs[i + 1] < (u32)TOPK) Bsh = (u32)i;
        }
    }
    __syncthreads();
    // publish sufG[0..576] + B (dispatch boundary releases to k_binrank)
    sufG[t] = cs[t];
    sufG[t + 256] = cs[t + 256];
    if (t + 512 <= H1_BINS) sufG[t + 512] = cs[t + 512];   // includes 576
    if (t == 0) sufG[577] = Bsh;
}

// ============ k_binrank: R10-verified gather+rank (preamble-free) ============
__global__ void __launch_bounds__(256) k_binrank(const u64* __restrict__ selBins,
                                                 const u32* __restrict__ binCur,
                                                 const u32* __restrict__ sufG,
                                                 const float* __restrict__ boxes,
                                                 float* __restrict__ rboxes,
                                                 float* __restrict__ rvals,
                                                 int* __restrict__ rlabel,
                                                 float* __restrict__ out) {
    __shared__ u64 seg[SEG_LDS];                  // 32 KB
    __shared__ u32 sBase[NSLICE + 1];
    const int t = threadIdx.x;
    const u32 B = sufG[577];

    if (blockIdx.x == H1_BINS) {                  // tail block (degenerate fill)
        u32 covered = sufG[B];
        if (covered > (u32)TOPK) covered = TOPK;
        for (u32 r = covered + t; r < TOPK; r += 256) {
            rboxes[r * 4 + 0] = 0; rboxes[r * 4 + 1] = 0;
            rboxes[r * 4 + 2] = 0; rboxes[r * 4 + 3] = 0;
            rvals[r] = 0.0f; rlabel[r] = 0;
            out[TOPK * 5 + r] = 0.0f;
            out[TOPK * 6 + r] = 0.0f;
            float* d = out + (size_t)r * 5;
            d[0] = 0; d[1] = 0; d[2] = 0; d[3] = 0; d[4] = 0;
        }
        return;
    }

    const u32 b = blockIdx.x;
    if (b < B) return;                            // rank >= TOPK guaranteed
    u32 start = sufG[b + 1];
    u32 end = sufG[b];
    if (start >= end) return;                     // empty bin
    if (start >= (u32)TOPK) return;

    // ---- gather own bin from 32 slice segments into LDS (R3-verified) ----
    if (t < NSLICE) {                             // all in wave 0
        u32 c0s = binCur[t * H1_BINS + b];
        if (c0s > (u32)SUBCAP) c0s = SUBCAP;      // stored count
        u32 inc = c0s;
        #pragma unroll
        for (int d = 1; d < NSLICE; d <<= 1) {
            u32 o = __shfl_up(inc, d);
            if (t >= d) inc += o;
        }
        sBase[t] = inc - c0s;
        if (t == NSLICE - 1) sBase[NSLICE] = inc;
    }
    __syncthreads();
    const u32 lenSt = sBase[NSLICE];
    const u32 ldsLen = lenSt < (u32)SEG_LDS ? lenSt : (u32)SEG_LDS;
    {
        const u32 s = (u32)t >> 3;                // 8 threads per slice
        const u32 base = sBase[s];
        const u32 cntS = sBase[s + 1] - base;
        const u64* gs = selBins + ((size_t)s * H1_BINS + b) * SUBCAP;
        for (u32 i = (u32)t & 7u; i < cntS; i += 8u) {
            u32 d = base + i;
            if (d < (u32)SEG_LDS) seg[d] = gs[i];
        }
    }
    __syncthreads();

    // ---- quadratic rank + emit (R3-verified; overflow caps unreachable) ----
    for (u32 i = (u32)t; i < ldsLen; i += 256) {
        u64 c = seg[i];
        u32 r0 = 0;
        for (u32 j = 0; j < ldsLen; j++) r0 += (seg[j] > c) ? 1u : 0u;
        u32 r = start + r0;
        if (r >= (u32)TOPK) continue;             // bin-B overflow: below cutoff
        u32 idx = 0xFFFFFFFFu - (u32)(c & 0xFFFFFFFFull);
        float val = __uint_as_float((u32)(c >> 32));
        u32 bi = idx / NCLS;
        u32 lab = idx % NCLS;
        const float* bp = boxes + (size_t)bi * 4;
        float x1 = fminf(fmaxf(bp[0], 0.0f), IMGW_M1);
        float y1 = fminf(fmaxf(bp[1], 0.0f), IMGH_M1);
        float x2 = fminf(fmaxf(bp[2], 0.0f), IMGW_M1);
        float y2 = fminf(fmaxf(bp[3], 0.0f), IMGH_M1);
        rboxes[r * 4 + 0] = x1; rboxes[r * 4 + 1] = y1;
        rboxes[r * 4 + 2] = x2; rboxes[r * 4 + 3] = y2;
        rvals[r] = val;
        rlabel[r] = (int)lab;
        out[TOPK * 5 + r] = (float)lab;           // labels (unmasked in reference)
    }
}

// ============ k_nms: EXACT R3-verified kernel ============
__device__ inline float4 nms_box(u32 g, const float4* __restrict__ boxL,
                                 const float* __restrict__ rboxes,
                                 const unsigned short* __restrict__ memRank, float off) {
    if (g < (u32)MCAP) return boxL[g];
    float4 b = ((const float4*)rboxes)[memRank[g]];     // fallback: never in practice
    return make_float4(b.x + off, b.y + off, b.z + off, b.w + off);
}
__device__ inline float nms_area(u32 g, const float* __restrict__ areaL, float4 b) {
    if (g < (u32)MCAP) return areaL[g];
    return (b.z - b.x) * (b.w - b.y);
}

__global__ void __launch_bounds__(256) k_nms(const float* __restrict__ rboxes,
                                             const float* __restrict__ rvals,
                                             const int* __restrict__ rlabel,
                                             float* __restrict__ out) {
    int c = blockIdx.x + 1;                     // labels 1..80
    __shared__ int lLab[TOPK];                  // 16 KB
    __shared__ float4 boxL[MCAP];               // 16 KB (offset boxes)
    __shared__ float areaL[MCAP];               // 4 KB
    __shared__ unsigned short memRank[TOPK];    // 8 KB
    __shared__ u32 colW[MMAX * NW32];           // 32 KB column-mask words
    __shared__ u32 remOut[NW32];
    __shared__ unsigned char keepL[TOPK];       // fallback only
    __shared__ u32 cc[64];
    __shared__ u32 baseC[64];
    __shared__ u32 mTotSh;
    const int t = threadIdx.x;
    const int w = t >> 6, lane = t & 63;
    const u64 laneLT = ((u64)1 << lane) - 1;
    const float off = (float)c * 4096.0f;       // reference's f32 offset rounding

    // stage labels into LDS (coalesced int4) — ballot rounds then hit LDS
    {
        const int4* g4 = (const int4*)rlabel;
        int4* l4 = (int4*)lLab;
        for (int i = t; i < TOPK / 4; i += 256) l4[i] = g4[i];
    }
    __syncthreads();

    // phase A: per-64-chunk counts
    for (int it = 0; it < 16; it++) {
        int chunk = it * 4 + w;
        int r = chunk * 64 + lane;
        u64 mask = __ballot(lLab[r] == c);
        if (lane == 0) cc[chunk] = (u32)__popcll(mask);
    }
    __syncthreads();
    // phase B: exclusive scan of 64 chunk counts (wave 0)
    if (t < 64) {
        u32 v = cc[t];
        u32 inc = v;
        #pragma unroll
        for (int d = 1; d < 64; d <<= 1) {
            u32 o = __shfl_up(inc, d);
            if (lane >= d) inc += o;
        }
        baseC[t] = inc - v;
        if (t == 63) mTotSh = inc;
    }
    __syncthreads();
    const u32 m = mTotSh;
    // phase C: stable scatter + stage offset boxes/areas
    for (int it = 0; it < 16; it++) {
        int chunk = it * 4 + w;
        int r = chunk * 64 + lane;
        bool match = (lLab[r] == c);
        u64 mask = __ballot(match);
        if (match) {
            u32 g = baseC[chunk] + (u32)__popcll(mask & laneLT);
            memRank[g] = (unsigned short)r;
            if (g < (u32)MCAP) {
                float4 b = ((const float4*)rboxes)[r];
                float bx1 = b.x + off, by1 = b.y + off;
                float bx2 = b.z + off, by2 = b.w + off;
                boxL[g] = make_float4(bx1, by1, bx2, by2);
                areaL[g] = (bx2 - bx1) * (by2 - by1);   // reference: area on offset boxes
            }
        }
    }
    __syncthreads();

    const bool matrixPath = (m <= (u32)MMAX);
    if (matrixPath) {
        const u32 nW = (m + 31) >> 5;
        const u32 items = m * nW;
        // parallel column-mask build: item (s, wd) -> one 32-bit word
        for (u32 p = t; p < items; p += 256) {
            u32 s = p / nW;
            u32 wd = p - s * nW;
            float4 bs = nms_box(s, boxL, rboxes, memRank, off);
            float as = nms_area(s, areaL, bs);
            u32 word = 0;
            u32 j0 = wd << 5;
            u32 jend = j0 + 32; if (jend > m) jend = m;
            u32 js = (j0 > s + 1) ? j0 : (s + 1);
            for (u32 j = js; j < jend; j++) {
                float4 bj = nms_box(j, boxL, rboxes, memRank, off);
                float aj = nms_area(j, areaL, bj);
                float iw = fmaxf(fminf(bs.z, bj.z) - fmaxf(bs.x, bj.x), 0.0f);
                float ih = fmaxf(fminf(bs.w, bj.w) - fmaxf(bs.y, bj.y), 0.0f);
                float inter = iw * ih;
                float iou = inter / (as + aj - inter + 1e-9f);  // area_s + area_j: ref order
                if (iou > 0.5f) word |= (1u << (j - j0));
            }
            colW[s * NW32 + wd] = word;
        }
        __syncthreads();
        // greedy scan: wave 0, lane w holds rem-word w; shuffle-broadcast removed bit
        if (t < 64) {
            u32 remW = 0;
            bool own = ((u32)lane < ((m + 31) >> 5));
            for (u32 s2 = 0; s2 < m; s2++) {
                u32 rw = __shfl(remW, (int)(s2 >> 5));
                bool removed = (rw >> (s2 & 31)) & 1u;
                u32 cw = own ? colW[s2 * NW32 + lane] : 0u;
                if (!removed) remW |= cw;
            }
            if (own) remOut[lane] = remW;
        }
        __syncthreads();
    } else {
        // fallback (m > 512: statistically unreachable) — reference-style scan
        for (u32 q2 = t; q2 < m; q2 += 256) keepL[q2] = 1;
        __syncthreads();
        for (u32 i = 0; i < m; i++) {
            __syncthreads();
            if (!keepL[i]) continue;                 // uniform (shared value)
            float4 bi = nms_box(i, boxL, rboxes, memRank, off);
            float ai = nms_area(i, areaL, bi);
            for (u32 jj = i + 1 + t; jj < m; jj += 256) {
                if (!keepL[jj]) continue;
                float4 bj = nms_box(jj, boxL, rboxes, memRank, off);
                float aj = nms_area(jj, areaL, bj);
                float iw = fmaxf(fminf(bi.z, bj.z) - fmaxf(bi.x, bj.x), 0.0f);
                float ih = fmaxf(fminf(bi.w, bj.w) - fmaxf(bi.y, bj.y), 0.0f);
                float inter = iw * ih;
                float iou = inter / (ai + aj - inter + 1e-9f);
                if (iou > 0.5f) keepL[jj] = 0;
            }
        }
        __syncthreads();
    }

    // output
    for (u32 q2 = t; q2 < m; q2 += 256) {
        bool keep = matrixPath ? !((remOut[q2 >> 5] >> (q2 & 31)) & 1u)
                               : (keepL[q2] != 0);
        int r = memRank[q2];
        out[TOPK * 6 + r] = keep ? 1.0f : 0.0f;
        float* d = out + (size_t)r * 5;
        if (keep) {
            float4 b = ((const float4*)rboxes)[r];
            d[0] = b.x; d[1] = b.y; d[2] = b.z; d[3] = b.w;
            d[4] = rvals[r];
        } else {
            d[0] = 0; d[1] = 0; d[2] = 0; d[3] = 0; d[4] = 0;
        }
    }
}

extern "C" void kernel_launch(void* const* d_in, const int* in_sizes, int n_in,
                              void* d_out, int out_size, void* d_ws, size_t ws_size,
                              hipStream_t stream) {
    const float* x = (const float*)d_in[0];
    const float* boxes = (const float*)d_in[1];
    float* out = (float*)d_out;

    u32* W = (u32*)d_ws;
    u32* tick1 = W;                                        // 32 u32 (zeroed)
    u32* tick2 = W + 32;                                   // 1 u32 (zeroed)
    u32* sufG = W + 64;                                    // 578 u32 (zeroed)
    u32* binCur = W + 1024;                                // 32*576 u32 (zeroed)
    u64* selBins = (u64*)((char*)d_ws + 131072);           // 32*576*SUBCAP u64 (~56.6 MB)
    float* rboxes = (float*)(selBins + (size_t)NSLICE * H1_BINS * SUBCAP);  // 16384 f32
    float* rvals = rboxes + 4 * TOPK;                      // 4096
    int* rlabel = (int*)(rvals + TOPK);                    // 4096

    // zero: tickets + sufG + binCur (one contiguous 77.8 KB fill)
    hipMemsetAsync(W, 0, 4096 + NSLICE * H1_BINS * sizeof(u32), stream);
    k_cand<<<CAND_GRID, CAND_THREADS, 0, stream>>>(x, binCur, selBins,
                                                   tick1, tick2, sufG);
    k_binrank<<<H1_BINS + 1, 256, 0, stream>>>(selBins, binCur, sufG, boxes,
                                               rboxes, rvals, rlabel, out);
    k_nms<<<80, 256, 0, stream>>>(rboxes, rvals, rlabel, out);
}

// Round 13
// 94.379 us; speedup vs baseline: 1.6896x; 1.6896x over previous
//
#include <hip/hip_runtime.h>

#pragma clang fp contract(off)

typedef unsigned int u32;
typedef unsigned long long u64;
typedef long long i64;

#define N_ROWS 32768
#define NCLS 81
#define TOPK 4096
#define IMGW_M1 1332.0f
#define IMGH_M1 799.0f

// k_cand geometry: 8 threads/row, 32 rows/block, 1024 blocks (R3-verified)
#define CAND_THREADS 256
#define RPB 32
#define CAND_GRID (N_ROWS / RPB)          // 1024
#define CPT 11
#define BLK_CAND_CAP 640                  // 32 rows * <=19 cand/row = 608 max
#define ROW_F4 ((RPB * NCLS) / 4)         // 648 float4 per block slice (exactly)

// level-1 bins: f32 bits of p in (0.05, 1.0] -> hi16 in [0x3D4C, 0x3F80]
#define H1_BASE 0x3D4Cu
#define H1_BINS 576

// sliced per-bin segments (R3-verified best: 32)
#define NSLICE 32
#define SUBCAP 384                        // per-slice-per-bin capacity (u64)
#define SEG_LDS 4096                      // binrank LDS segment cap (u64)

// k_nms: LDS box stage cap / matrix-path cap
#define MCAP 1024
#define MMAX 512
#define NW32 16                           // MMAX/32 words per column

// fast f64 exp for d <= 0 (clamped at -45). Cody-Waite + Taylor-13.
// Relative error ~3e-16 — decisions have >= f32-ulp (6e-8) margins.
__device__ inline double fast_exp_neg(double d) {
    if (d < -45.0) return 0.0;
    const double L2E    = 1.4426950408889634074;
    const double LN2_HI = 6.93147180369123816490e-01;
    const double LN2_LO = 1.90821492927058770002e-10;
    double n = __builtin_rint(d * L2E);
    double r = __builtin_fma(-n, LN2_HI, d);
    r = __builtin_fma(-n, LN2_LO, r);
    double p = 1.0 / 6227020800.0;
    p = __builtin_fma(p, r, 1.0 / 479001600.0);
    p = __builtin_fma(p, r, 1.0 / 39916800.0);
    p = __builtin_fma(p, r, 1.0 / 3628800.0);
    p = __builtin_fma(p, r, 1.0 / 362880.0);
    p = __builtin_fma(p, r, 1.0 / 40320.0);
    p = __builtin_fma(p, r, 1.0 / 5040.0);
    p = __builtin_fma(p, r, 1.0 / 720.0);
    p = __builtin_fma(p, r, 1.0 / 120.0);
    p = __builtin_fma(p, r, 1.0 / 24.0);
    p = __builtin_fma(p, r, 1.0 / 6.0);
    p = __builtin_fma(p, r, 0.5);
    p = __builtin_fma(p, r, 1.0);
    p = __builtin_fma(p, r, 1.0);
    i64 ni = (i64)n;
    double sc = __longlong_as_double((i64)(1023 + ni) << 52);
    return p * sc;
}

// ============ k_cand: EXACT R3/R10-verified kernel ============
__global__ void __launch_bounds__(256) k_cand(const float* __restrict__ x,
                                              u32* __restrict__ binCur,
                                              u64* __restrict__ selBins) {
    __shared__ float4 lx4[ROW_F4];
    __shared__ u32 lK[BLK_CAND_CAP];
    __shared__ u32 lI[BLK_CAND_CAP];
    __shared__ u32 lcnt;
    float* lx = (float*)lx4;
    const int t = threadIdx.x;
    if (t == 0) lcnt = 0;

    const float4* xv = (const float4*)x + (size_t)blockIdx.x * ROW_F4;
    for (int i = t; i < ROW_F4; i += CAND_THREADS) lx4[i] = xv[i];
    __syncthreads();

    const int rl = t >> 3;
    const int q = t & 7;
    const int c0 = q * 10;
    const int cEff = (q == 7) ? 11 : 10;
    const int row = blockIdx.x * RPB + rl;
    const float* xr = lx + rl * NCLS;

    float v[CPT];
    #pragma unroll
    for (int i = 0; i < CPT; i++) v[i] = (i < cEff) ? xr[c0 + i] : -1.0e30f;

    float m = v[0];
    #pragma unroll
    for (int i = 1; i < CPT; i++) m = fmaxf(m, v[i]);
    m = fmaxf(m, __shfl_xor(m, 1));
    m = fmaxf(m, __shfl_xor(m, 2));
    m = fmaxf(m, __shfl_xor(m, 4));

    double e[CPT];
    #pragma unroll
    for (int i = 0; i < CPT; i++) {
        if (i < cEff) {
            float d = v[i] - m;                   // f32 subtract, as reference
            e[i] = fast_exp_neg((double)d);
        } else e[i] = 0.0;
    }
    double s = 0.0;
    #pragma unroll
    for (int i = 0; i < CPT; i++) if (i < cEff) s += e[i];
    s += __shfl_xor(s, 1);
    s += __shfl_xor(s, 2);
    s += __shfl_xor(s, 4);

    const double THRMID = (double)0.05f + 0x1.0p-29;
    double ethr = THRMID * s;
    #pragma unroll
    for (int i = 0; i < CPT; i++) {
        int c = c0 + i;
        if (i < cEff && c != 0 && e[i] > ethr) {
            float pf = (float)(e[i] / s);         // exact f64 division, rare
            u32 slot = atomicAdd(&lcnt, 1u);
            lK[slot] = __float_as_uint(pf);
            lI[slot] = (u32)(row * NCLS + c);
        }
    }
    __syncthreads();

    // sliced scatter: wave lanes hit DISTINCT staged cands;
    // per-address chains <= ~44 (hot bin / 32 slices)
    const u32 tot = lcnt;
    const u32 sbase = (blockIdx.x & (NSLICE - 1)) * H1_BINS;
    for (u32 i = t; i < tot; i += CAND_THREADS) {
        u32 key = lK[i];
        u32 b = (key >> 16) - H1_BASE;            // always in [0, 576)
        u32 pos = atomicAdd(&binCur[sbase + b], 1u);
        if (pos < (u32)SUBCAP)
            selBins[(size_t)(sbase + b) * SUBCAP + pos] =
                ((u64)key << 32) | (u64)(0xFFFFFFFFu - lI[i]);
    }
}

// ============ k_midlite: R10-verified single-block reduce+scan ============
__global__ void __launch_bounds__(1024) k_midlite(const u32* __restrict__ binCur,
                                                  u32* __restrict__ sufG) {
    __shared__ u32 cs[1024];
    int t = threadIdx.x;
    u32 s1 = 0;
    if (t < H1_BINS) {
        for (int j = 0; j < NSLICE; j++) s1 += binCur[j * H1_BINS + t];  // coalesced
    }
    cs[t] = (t < H1_BINS) ? s1 : 0u;
    __syncthreads();
    for (int d = 1; d < 1024; d <<= 1) {          // inclusive suffix sum
        u32 v = (t + d < 1024) ? cs[t + d] : 0u;
        __syncthreads();
        cs[t] += v;
        __syncthreads();
    }
    if (t < 577) sufG[t] = cs[t];                 // cs[576] == 0 naturally
    u32 S_t = cs[t];
    u32 S_next = (t < 1023) ? cs[t + 1] : 0u;
    if (S_next < TOPK && S_t >= TOPK) sufG[577] = (u32)t;  // cutoff bin B
}

// ============ k_binrank: preamble-free (R10) + COUNTING rank (R7-verified) ==
// Per bin: histogram next-8 key bits (c[47:40]) into 256 sub-bins, suffix
// scan, scatter sub-bin-ordered into seg, rank = suf(sub+1) + #greater within
// own ~6-item sub-segment. Same strict total order -> bit-identical output
// (R7 run passed with this exact rank body).
__global__ void __launch_bounds__(256) k_binrank(const u64* __restrict__ selBins,
                                                 const u32* __restrict__ binCur,
                                                 const u32* __restrict__ sufG,
                                                 const float* __restrict__ boxes,
                                                 float* __restrict__ rboxes,
                                                 float* __restrict__ rvals,
                                                 int* __restrict__ rlabel,
                                                 float* __restrict__ out) {
    __shared__ u64 seg[SEG_LDS];                  // 32 KB, sub-bin-ordered
    __shared__ u32 h2[256];                       // sub-bin counts -> suffix sums
    __shared__ u32 cur2[256];                     // scatter cursors
    __shared__ u32 sBase[NSLICE + 1];
    const int t = threadIdx.x;
    const u32 B = sufG[577];

    if (blockIdx.x == H1_BINS) {                  // tail block (degenerate fill)
        u32 covered = sufG[B];
        if (covered > (u32)TOPK) covered = TOPK;
        for (u32 r = covered + t; r < TOPK; r += 256) {
            rboxes[r * 4 + 0] = 0; rboxes[r * 4 + 1] = 0;
            rboxes[r * 4 + 2] = 0; rboxes[r * 4 + 3] = 0;
            rvals[r] = 0.0f; rlabel[r] = 0;
            out[TOPK * 5 + r] = 0.0f;
            out[TOPK * 6 + r] = 0.0f;
            float* d = out + (size_t)r * 5;
            d[0] = 0; d[1] = 0; d[2] = 0; d[3] = 0; d[4] = 0;
        }
        return;
    }

    const u32 b = blockIdx.x;
    if (b < B) return;                            // rank >= TOPK guaranteed
    u32 start = sufG[b + 1];
    u32 end = sufG[b];
    if (start >= end) return;                     // empty bin
    if (start >= (u32)TOPK) return;

    // ---- slice bases (wave-0 scan over 32 stored counts; R3-verified) ----
    if (t < NSLICE) {
        u32 c0s = binCur[t * H1_BINS + b];
        if (c0s > (u32)SUBCAP) c0s = SUBCAP;      // stored count
        u32 inc = c0s;
        #pragma unroll
        for (int d = 1; d < NSLICE; d <<= 1) {
            u32 o = __shfl_up(inc, d);
            if (t >= d) inc += o;
        }
        sBase[t] = inc - c0s;
        if (t == NSLICE - 1) sBase[NSLICE] = inc;
    }
    h2[t] = 0;
    cur2[t] = 0;
    __syncthreads();
    const u32 lenSt = sBase[NSLICE];
    const u32 ldsLen = lenSt < (u32)SEG_LDS ? lenSt : (u32)SEG_LDS;

    // ---- sub-bin histogram (global read 1, L2-hot; R7-verified) ----
    {
        const u32 s = (u32)t >> 3;                // 8 threads per slice
        const u32 cntS = sBase[s + 1] - sBase[s];
        const u64* gs = selBins + ((size_t)s * H1_BINS + b) * SUBCAP;
        for (u32 i = (u32)t & 7u; i < cntS; i += 8u) {
            u32 s2 = (u32)(gs[i] >> 40) & 0xFFu;  // key bits [15:8]
            atomicAdd(&h2[s2], 1u);
        }
    }
    __syncthreads();
    // ---- inclusive suffix scan of h2 (8 steps; R7-verified) ----
    for (int d = 1; d < 256; d <<= 1) {
        u32 o = (t + d < 256) ? h2[t + d] : 0u;
        __syncthreads();
        h2[t] += o;
        __syncthreads();
    }
    // h2[k] = #items with sub-bin >= k; sub-bin k's segment = [suf(k+1), h2[k])

    // ---- scatter sub-bin-ordered (global read 2; R7-verified) ----
    {
        const u32 s = (u32)t >> 3;
        const u32 cntS = sBase[s + 1] - sBase[s];
        const u64* gs = selBins + ((size_t)s * H1_BINS + b) * SUBCAP;
        for (u32 i = (u32)t & 7u; i < cntS; i += 8u) {
            u64 c = gs[i];
            u32 s2 = (u32)(c >> 40) & 0xFFu;
            u32 lo = (s2 < 255u) ? h2[s2 + 1] : 0u;
            u32 pos = lo + atomicAdd(&cur2[s2], 1u);
            if (pos < (u32)SEG_LDS) seg[pos] = c;
        }
    }
    __syncthreads();

    // ---- rank within ~6-item sub-segment + emit (R7-verified) ----
    for (u32 i = (u32)t; i < ldsLen; i += 256) {
        u64 c = seg[i];
        u32 s2 = (u32)(c >> 40) & 0xFFu;
        u32 lo = (s2 < 255u) ? h2[s2 + 1] : 0u;
        u32 hi = h2[s2];
        if (hi > ldsLen) hi = ldsLen;
        u32 r0 = lo;
        for (u32 j = lo; j < hi; j++) r0 += (seg[j] > c) ? 1u : 0u;
        u32 r = start + r0;
        if (r >= (u32)TOPK) continue;             // bin-B overflow: below cutoff
        u32 idx = 0xFFFFFFFFu - (u32)(c & 0xFFFFFFFFull);
        float val = __uint_as_float((u32)(c >> 32));
        u32 bi = idx / NCLS;
        u32 lab = idx % NCLS;
        const float* bp = boxes + (size_t)bi * 4;
        float x1 = fminf(fmaxf(bp[0], 0.0f), IMGW_M1);
        float y1 = fminf(fmaxf(bp[1], 0.0f), IMGH_M1);
        float x2 = fminf(fmaxf(bp[2], 0.0f), IMGW_M1);
        float y2 = fminf(fmaxf(bp[3], 0.0f), IMGH_M1);
        rboxes[r * 4 + 0] = x1; rboxes[r * 4 + 1] = y1;
        rboxes[r * 4 + 2] = x2; rboxes[r * 4 + 3] = y2;
        rvals[r] = val;
        rlabel[r] = (int)lab;
        out[TOPK * 5 + r] = (float)lab;           // labels (unmasked in reference)
    }
}

// ============ k_nms: EXACT R3/R10-verified kernel ============
__device__ inline float4 nms_box(u32 g, const float4* __restrict__ boxL,
                                 const float* __restrict__ rboxes,
                                 const unsigned short* __restrict__ memRank, float off) {
    if (g < (u32)MCAP) return boxL[g];
    float4 b = ((const float4*)rboxes)[memRank[g]];     // fallback: never in practice
    return make_float4(b.x + off, b.y + off, b.z + off, b.w + off);
}
__device__ inline float nms_area(u32 g, const float* __restrict__ areaL, float4 b) {
    if (g < (u32)MCAP) return areaL[g];
    return (b.z - b.x) * (b.w - b.y);
}

__global__ void __launch_bounds__(256) k_nms(const float* __restrict__ rboxes,
                                             const float* __restrict__ rvals,
                                             const int* __restrict__ rlabel,
                                             float* __restrict__ out) {
    int c = blockIdx.x + 1;                     // labels 1..80
    __shared__ int lLab[TOPK];                  // 16 KB
    __shared__ float4 boxL[MCAP];               // 16 KB (offset boxes)
    __shared__ float areaL[MCAP];               // 4 KB
    __shared__ unsigned short memRank[TOPK];    // 8 KB
    __shared__ u32 colW[MMAX * NW32];           // 32 KB column-mask words
    __shared__ u32 remOut[NW32];
    __shared__ unsigned char keepL[TOPK];       // fallback only
    __shared__ u32 cc[64];
    __shared__ u32 baseC[64];
    __shared__ u32 mTotSh;
    const int t = threadIdx.x;
    const int w = t >> 6, lane = t & 63;
    const u64 laneLT = ((u64)1 << lane) - 1;
    const float off = (float)c * 4096.0f;       // reference's f32 offset rounding

    // stage labels into LDS (coalesced int4) — ballot rounds then hit LDS
    {
        const int4* g4 = (const int4*)rlabel;
        int4* l4 = (int4*)lLab;
        for (int i = t; i < TOPK / 4; i += 256) l4[i] = g4[i];
    }
    __syncthreads();

    // phase A: per-64-chunk counts
    for (int it = 0; it < 16; it++) {
        int chunk = it * 4 + w;
        int r = chunk * 64 + lane;
        u64 mask = __ballot(lLab[r] == c);
        if (lane == 0) cc[chunk] = (u32)__popcll(mask);
    }
    __syncthreads();
    // phase B: exclusive scan of 64 chunk counts (wave 0)
    if (t < 64) {
        u32 v = cc[t];
        u32 inc = v;
        #pragma unroll
        for (int d = 1; d < 64; d <<= 1) {
            u32 o = __shfl_up(inc, d);
            if (lane >= d) inc += o;
        }
        baseC[t] = inc - v;
        if (t == 63) mTotSh = inc;
    }
    __syncthreads();
    const u32 m = mTotSh;
    // phase C: stable scatter + stage offset boxes/areas
    for (int it = 0; it < 16; it++) {
        int chunk = it * 4 + w;
        int r = chunk * 64 + lane;
        bool match = (lLab[r] == c);
        u64 mask = __ballot(match);
        if (match) {
            u32 g = baseC[chunk] + (u32)__popcll(mask & laneLT);
            memRank[g] = (unsigned short)r;
            if (g < (u32)MCAP) {
                float4 b = ((const float4*)rboxes)[r];
                float bx1 = b.x + off, by1 = b.y + off;
                float bx2 = b.z + off, by2 = b.w + off;
                boxL[g] = make_float4(bx1, by1, bx2, by2);
                areaL[g] = (bx2 - bx1) * (by2 - by1);   // reference: area on offset boxes
            }
        }
    }
    __syncthreads();

    const bool matrixPath = (m <= (u32)MMAX);
    if (matrixPath) {
        const u32 nW = (m + 31) >> 5;
        const u32 items = m * nW;
        // parallel column-mask build: item (s, wd) -> one 32-bit word
        for (u32 p = t; p < items; p += 256) {
            u32 s = p / nW;
            u32 wd = p - s * nW;
            float4 bs = nms_box(s, boxL, rboxes, memRank, off);
            float as = nms_area(s, areaL, bs);
            u32 word = 0;
            u32 j0 = wd << 5;
            u32 jend = j0 + 32; if (jend > m) jend = m;
            u32 js = (j0 > s + 1) ? j0 : (s + 1);
            for (u32 j = js; j < jend; j++) {
                float4 bj = nms_box(j, boxL, rboxes, memRank, off);
                float aj = nms_area(j, areaL, bj);
                float iw = fmaxf(fminf(bs.z, bj.z) - fmaxf(bs.x, bj.x), 0.0f);
                float ih = fmaxf(fminf(bs.w, bj.w) - fmaxf(bs.y, bj.y), 0.0f);
                float inter = iw * ih;
                float iou = inter / (as + aj - inter + 1e-9f);  // area_s + area_j: ref order
                if (iou > 0.5f) word |= (1u << (j - j0));
            }
            colW[s * NW32 + wd] = word;
        }
        __syncthreads();
        // greedy scan: wave 0, lane w holds rem-word w; shuffle-broadcast removed bit
        if (t < 64) {
            u32 remW = 0;
            bool own = ((u32)lane < ((m + 31) >> 5));
            for (u32 s2 = 0; s2 < m; s2++) {
                u32 rw = __shfl(remW, (int)(s2 >> 5));
                bool removed = (rw >> (s2 & 31)) & 1u;
                u32 cw = own ? colW[s2 * NW32 + lane] : 0u;
                if (!removed) remW |= cw;
            }
            if (own) remOut[lane] = remW;
        }
        __syncthreads();
    } else {
        // fallback (m > 512: statistically unreachable) — reference-style scan
        for (u32 q2 = t; q2 < m; q2 += 256) keepL[q2] = 1;
        __syncthreads();
        for (u32 i = 0; i < m; i++) {
            __syncthreads();
            if (!keepL[i]) continue;                 // uniform (shared value)
            float4 bi = nms_box(i, boxL, rboxes, memRank, off);
            float ai = nms_area(i, areaL, bi);
            for (u32 jj = i + 1 + t; jj < m; jj += 256) {
                if (!keepL[jj]) continue;
                float4 bj = nms_box(jj, boxL, rboxes, memRank, off);
                float aj = nms_area(jj, areaL, bj);
                float iw = fmaxf(fminf(bi.z, bj.z) - fmaxf(bi.x, bj.x), 0.0f);
                float ih = fmaxf(fminf(bi.w, bj.w) - fmaxf(bi.y, bj.y), 0.0f);
                float inter = iw * ih;
                float iou = inter / (ai + aj - inter + 1e-9f);
                if (iou > 0.5f) keepL[jj] = 0;
            }
        }
        __syncthreads();
    }

    // output
    for (u32 q2 = t; q2 < m; q2 += 256) {
        bool keep = matrixPath ? !((remOut[q2 >> 5] >> (q2 & 31)) & 1u)
                               : (keepL[q2] != 0);
        int r = memRank[q2];
        out[TOPK * 6 + r] = keep ? 1.0f : 0.0f;
        float* d = out + (size_t)r * 5;
        if (keep) {
            float4 b = ((const float4*)rboxes)[r];
            d[0] = b.x; d[1] = b.y; d[2] = b.z; d[3] = b.w;
            d[4] = rvals[r];
        } else {
            d[0] = 0; d[1] = 0; d[2] = 0; d[3] = 0; d[4] = 0;
        }
    }
}

extern "C" void kernel_launch(void* const* d_in, const int* in_sizes, int n_in,
                              void* d_out, int out_size, void* d_ws, size_t ws_size,
                              hipStream_t stream) {
    const float* x = (const float*)d_in[0];
    const float* boxes = (const float*)d_in[1];
    float* out = (float*)d_out;

    u32* W = (u32*)d_ws;
    u32* sufG = W + 16;                                    // 578 u32 (zeroed: B default 0)
    u32* binCur = W + 1024;                                // 32*576 u32 (zeroed)
    u64* selBins = (u64*)((char*)d_ws + 131072);           // 32*576*SUBCAP u64 (~56.6 MB)
    float* rboxes = (float*)(selBins + (size_t)NSLICE * H1_BINS * SUBCAP);  // 16384 f32
    float* rvals = rboxes + 4 * TOPK;                      // 4096
    int* rlabel = (int*)(rvals + TOPK);                    // 4096

    // zero: sufG + binCur (one contiguous 77.8 KB fill)
    hipMemsetAsync(W, 0, 4096 + NSLICE * H1_BINS * sizeof(u32), stream);
    k_cand<<<CAND_GRID, CAND_THREADS, 0, stream>>>(x, binCur, selBins);
    k_midlite<<<1, 1024, 0, stream>>>(binCur, sufG);
    k_binrank<<<H1_BINS + 1, 256, 0, stream>>>(selBins, binCur, sufG, boxes,
                                               rboxes, rvals, rlabel, out);
    k_nms<<<80, 256, 0, stream>>>(rboxes, rvals, rlabel, out);
}